// Round 15
// baseline (331.494 us; speedup 1.0000x reference)
//
#include <hip/hip_runtime.h>
#include <hip/hip_bf16.h>

// ---------------------------------------------------------------------------
// B=32, LQ=1024, LIN=5376, D=256, NH=8, L=3, P=4, DH=32, NH_CA=2, M=10, NCLS=200
// Outputs (f32): out[6400) | attn_u[320) | attn_n[320) | attn_s[327680)
// Round-14 structure (317us) + ONE change: spatial branch fused INTO msda
// (msda output was consumed only by spatial logits after the algebraic fold;
// compute logits from in-register acc[8], shfl-reduce per 32-lane query
// group, softmax on lane 0). Deletes msda buffer + spatial kernel.
// ---------------------------------------------------------------------------

typedef __attribute__((ext_vector_type(8))) short s16x8;
typedef __attribute__((ext_vector_type(4))) float f32x4;

__device__ __forceinline__ void store_val(float* p, float v) { *p = v; }
__device__ __forceinline__ void store_val(__hip_bfloat16* p, float v) { *p = __float2bfloat16(v); }

__device__ __forceinline__ unsigned short f2bf(float x) {
  unsigned int u = __builtin_bit_cast(unsigned int, x);
  u += 0x7FFFu + ((u >> 16) & 1u);  // RNE
  return (unsigned short)(u >> 16);
}
__device__ __forceinline__ float bf2f(unsigned short u) {
  return __builtin_bit_cast(float, (unsigned int)u << 16);
}
__device__ __forceinline__ float bflo(unsigned int u) {
  return __builtin_bit_cast(float, u << 16);
}
__device__ __forceinline__ float bfhi(unsigned int u) {
  return __builtin_bit_cast(float, u & 0xFFFF0000u);
}

__device__ __forceinline__ void gload16(const char* g, char* l) {
  __builtin_amdgcn_global_load_lds(
      (const __attribute__((address_space(1))) unsigned int*)g,
      (__attribute__((address_space(3))) unsigned int*)l, 16, 0, 0);
}

// ---------------------------------------------------------------------------
// prep_all: weight images (BK=64 layout) + bpack | kv | spatial fold.
// ---------------------------------------------------------------------------
__global__ __launch_bounds__(256) void prep_all(
    const float* __restrict__ W_val, const float* __restrict__ W_off,
    const float* __restrict__ b_off, const float* __restrict__ W_attn,
    const float* __restrict__ b_attn, char* __restrict__ imgV,
    char* __restrict__ imgQ, float* __restrict__ bpack,
    const float* __restrict__ unsup, const float* __restrict__ conc,
    const float* __restrict__ spat, const float* __restrict__ Wkv_c,
    const float* __restrict__ bkv_c, const float* __restrict__ Wkv_s,
    const float* __restrict__ bkv_s, float* __restrict__ kv_u,
    float* __restrict__ kv_n, float* __restrict__ kv_s,
    const float* __restrict__ Wq_s, const float* __restrict__ bq_s,
    const float* __restrict__ W_out, const float* __restrict__ b_out,
    float* __restrict__ WLt, float* __restrict__ WL2t, float* __restrict__ cL)
{
  const int bi = blockIdx.x;
  const int tid = threadIdx.x;
  if (bi <= 576) {
    const int n = bi, k = tid;
    if (n == 576) {
      bpack[k] = (k < 192) ? b_off[k] : ((k < 288) ? b_attn[k - 192] : 0.f);
      if (k < 64) bpack[256 + k] = (k < 32) ? b_attn[64 + k] : 0.f;
      return;
    }
    const int ks = k >> 6;
    const int kb = (k & 63) * 2;
    if (n < 256) {
      const unsigned short v = f2bf(W_val[(size_t)k * 256 + n]);
      *(unsigned short*)(imgV + ks * 32768 + n * 128 + (kb ^ ((n & 7) << 4))) = v;
    } else {
      const int c = n - 256;
      float v = 0.f;
      if (c < 192) v = W_off[(size_t)k * 192 + c];
      else if (c < 288) v = W_attn[(size_t)k * 96 + (c - 192)];
      *(unsigned short*)(imgQ + ks * 40960 + c * 128 + (kb ^ ((c & 7) << 4))) = f2bf(v);
    }
    return;
  }
  if (bi <= 579) {     // kv projections
    const int j = bi - 577;
    const float* src = (j == 0) ? unsup : ((j == 1) ? conc : spat);
    const float* W   = (j < 2) ? Wkv_c : Wkv_s;
    const float* bb  = (j < 2) ? bkv_c : bkv_s;
    float* dst       = (j == 0) ? kv_u : ((j == 1) ? kv_n : kv_s);
    __shared__ float s[2560];
    for (int i = tid; i < 2560; i += 256) s[i] = src[i];
    __syncthreads();
    for (int o = tid; o < 5120; o += 256) {
      const int m = o >> 9, n = o & 511;
      float acc = bb[n];
      for (int k = 0; k < 256; ++k) acc += s[m * 256 + k] * W[(size_t)k * 512 + n];
      dst[o] = acc;
    }
    return;
  }
  {                    // spatial fold
    const int j = bi - 580;
    const int h = j / 10, m = j % 10;
    __shared__ float kk[128], wl[256], bred[256];
    if (tid < 128) {
      const int n = h * 128 + tid;
      float acc = bkv_s[n];
      for (int k = 0; k < 256; ++k) acc += spat[m * 256 + k] * Wkv_s[(size_t)k * 512 + n];
      kk[tid] = acc;
    }
    __syncthreads();
    float acc = 0.f;
    for (int e = 0; e < 128; ++e) acc += Wq_s[(size_t)tid * 256 + h * 128 + e] * kk[e];
    wl[tid] = acc;
    __syncthreads();
    float acc2 = 0.f;
    for (int t = 0; t < 256; ++t) acc2 += W_out[(size_t)tid * 256 + t] * wl[t];
    const float scale = 0.08838834764831845f;
    WLt[j * 256 + tid] = scale * acc;
    WL2t[j * 256 + tid] = scale * acc2;
    bred[tid] = b_out[tid] * wl[tid] + ((tid < 128) ? bq_s[h * 128 + tid] * kk[tid] : 0.f);
    __syncthreads();
    for (int s = 128; s > 0; s >>= 1) {
      if (tid < s) bred[tid] += bred[tid + s];
      __syncthreads();
    }
    if (tid == 0) cL[j] = scale * bred[0];
  }
}

// ---------------------------------------------------------------------------
// GEMM (round-10/11 proven): C = A[M,256](f32) @ Bimg + bias.
// HM: head-major C layout [b*8+h][5376][32] (value GEMM only).
// ---------------------------------------------------------------------------
template <typename OT, int NCOLS, int MINW, bool HM>
__global__ __launch_bounds__(512, MINW) void gemm_f32a(
    const float* __restrict__ A, const char* __restrict__ Bimg,
    const float* __restrict__ bias, OT* __restrict__ C)
{
  constexpr int NFR = NCOLS / 64;
  __shared__ char sAf[32768];
  __shared__ char sBb[NCOLS * 128];

  const int tid = threadIdx.x;
  const int lane = tid & 63;
  const int w = tid >> 6;
  const int wr = (w >> 2) * 64;
  const int wc = (w & 3) * (NCOLS / 4);
  const int l15 = lane & 15;
  const int lg = lane >> 4;
  const int m0 = blockIdx.x * 128;

  int asrc[4];
#pragma unroll
  for (int i = 0; i < 4; ++i) {
    const int slot = w * 256 + i * 64 + lane;
    const int row = slot >> 4;
    const int c = (slot & 15) ^ (row & 7);
    asrc[i] = row * 256 + c * 4;
  }
  const float* Abase = A + (size_t)m0 * 256;

  f32x4 acc[4][NFR] = {};

#pragma unroll
  for (int ks = 0; ks < 4; ++ks) {
    if (ks) __syncthreads();
    {
      char* la = sAf + w * 4096;
#pragma unroll
      for (int i = 0; i < 4; ++i)
        gload16((const char*)(Abase + ks * 64 + asrc[i]), la + i * 1024);
      const char* gb = Bimg + ks * (NCOLS * 128) + w * (NCOLS * 16) + lane * 16;
      char* lb = sBb + w * (NCOLS * 16);
#pragma unroll
      for (int i = 0; i < NFR; ++i)
        gload16(gb + i * 1024, lb + i * 1024);
    }
    __syncthreads();
#pragma unroll
    for (int kk = 0; kk < 2; ++kk) {
      const int c0 = kk * 8 + lg * 2;
      s16x8 af[4];
#pragma unroll
      for (int mf = 0; mf < 4; ++mf) {
        const int row = wr + mf * 16 + l15;
        const int sw = row & 7;
        const f32x4 lo = *reinterpret_cast<const f32x4*>(
            sAf + row * 256 + ((c0 ^ sw) * 16));
        const f32x4 hi = *reinterpret_cast<const f32x4*>(
            sAf + row * 256 + (((c0 + 1) ^ sw) * 16));
        uint4 u;
        u.x = (unsigned)f2bf(lo[0]) | ((unsigned)f2bf(lo[1]) << 16);
        u.y = (unsigned)f2bf(lo[2]) | ((unsigned)f2bf(lo[3]) << 16);
        u.z = (unsigned)f2bf(hi[0]) | ((unsigned)f2bf(hi[1]) << 16);
        u.w = (unsigned)f2bf(hi[2]) | ((unsigned)f2bf(hi[3]) << 16);
        af[mf] = __builtin_bit_cast(s16x8, u);
      }
      const int kb = kk * 64 + lg * 16;
      s16x8 bf[NFR];
#pragma unroll
      for (int nf = 0; nf < NFR; ++nf) {
        const int col = wc + nf * 16 + l15;
        bf[nf] = *reinterpret_cast<const s16x8*>(sBb + col * 128 + (kb ^ ((col & 7) << 4)));
      }
#pragma unroll
      for (int mf = 0; mf < 4; ++mf)
#pragma unroll
        for (int nf = 0; nf < NFR; ++nf)
          acc[mf][nf] = __builtin_amdgcn_mfma_f32_16x16x32_bf16(af[mf], bf[nf], acc[mf][nf], 0, 0, 0);
    }
  }

#pragma unroll
  for (int nf = 0; nf < NFR; ++nf) {
    const int col = wc + nf * 16 + l15;
    const float bb = bias[col];
#pragma unroll
    for (int mf = 0; mf < 4; ++mf) {
#pragma unroll
      for (int j = 0; j < 4; ++j) {
        const int row = m0 + wr + mf * 16 + lg * 4 + j;
        const float v = acc[mf][nf][j] + bb;
        if constexpr (HM) {
          const unsigned rb = (unsigned)row / 5376u;
          const unsigned rr = (unsigned)row - rb * 5376u;
          store_val(&C[(((size_t)rb * 8 + (col >> 5)) * 5376 + rr) * 32 + (col & 31)], v);
        } else {
          store_val(&C[(size_t)row * NCOLS + col], v);
        }
      }
    }
  }
}

// ---------------------------------------------------------------------------
// MSDA + fused spatial: 8 queries/block. Gather (head-major value, depth-3
// gload_lds pipeline) -> acc[8] in registers -> spatial logits
// (query@WLt + acc@WL2t per 32-lane query group, shfl-reduce) -> softmax ->
// attn_s out + per-block abar partial [4096][20].
// ---------------------------------------------------------------------------
__global__ __launch_bounds__(256) void msda_sp(
    const float* __restrict__ offlog, const __hip_bfloat16* __restrict__ value,
    const float* __restrict__ query, const float* __restrict__ WLt,
    const float* __restrict__ WL2t, const float* __restrict__ cL,
    float* __restrict__ attn_out, float* __restrict__ partial)
{
  const int bq0 = blockIdx.x * 8;
  const int b = bq0 >> 10;
  const int tid = threadIdx.x;
  __shared__ float aw[768];
  __shared__ int4 sRow[768];
  __shared__ float4 sW[768];
  __shared__ __align__(16) char gbuf[4 * 3 * 4096];
  __shared__ float ared[8][20];

  if (tid < 64) {
    const int qi = tid >> 3, h = tid & 7;
    const float* lp = &offlog[(size_t)(bq0 + qi) * 320 + 192 + h * 12];
    float e[12];
    float mx = -1e30f;
#pragma unroll
    for (int i = 0; i < 12; ++i) { e[i] = lp[i]; mx = fmaxf(mx, e[i]); }
    float s = 0.f;
#pragma unroll
    for (int i = 0; i < 12; ++i) { e[i] = expf(e[i] - mx); s += e[i]; }
    const float inv = 1.f / s;
#pragma unroll
    for (int i = 0; i < 12; ++i) aw[qi * 96 + h * 12 + i] = e[i] * inv;
  }
  __syncthreads();

#pragma unroll
  for (int k = 0; k < 3; ++k) {
    const int j = k * 256 + tid;
    const int qi = j / 96, cc = j - qi * 96;
    const int q = (bq0 + qi) & 1023;
    const int h = cc / 12, r = cc - h * 12, l = r >> 2, p_ = r & 3;
    const int WHl[3] = {64, 32, 16};
    const int St[3] = {0, 4096, 5120};
    const float2 o2 = *reinterpret_cast<const float2*>(
        &offlog[(size_t)(bq0 + qi) * 320 + h * 24 + l * 8 + p_ * 2]);
    const float refx = ((q & 31) + 0.5f) * (1.0f / 32.0f);
    const float refy = ((q >> 5) + 0.5f) * (1.0f / 32.0f);
    const int WH = WHl[l];
    const float fw = (float)WH;
    const float lx = (refx + o2.x / fw) * fw - 0.5f;
    const float ly = (refy + o2.y / fw) * fw - 0.5f;
    const float fx = floorf(lx), fy = floorf(ly);
    const int x0 = (int)fx, y0 = (int)fy;
    const float dx = lx - fx, dy = ly - fy;
    const float a = aw[j];
    int rows[4];
    float ws[4];
#pragma unroll
    for (int c = 0; c < 4; ++c) {
      const int ix = x0 + (c & 1), iy = y0 + (c >> 1);
      const float wb = ((c & 1) ? dx : 1.f - dx) * ((c >> 1) ? dy : 1.f - dy);
      const bool valid = (ix >= 0) && (ix < WH) && (iy >= 0) && (iy < WH);
      const int cx = min(max(ix, 0), WH - 1);
      const int cy = min(max(iy, 0), WH - 1);
      rows[c] = St[l] + cy * WH + cx;
      ws[c] = valid ? wb * a : 0.f;
    }
    sRow[j] = int4{rows[0], rows[1], rows[2], rows[3]};
    sW[j] = float4{ws[0], ws[1], ws[2], ws[3]};
  }
  __syncthreads();

  const int w = tid >> 6;
  const int lane = tid & 63;
  const int qi = tid >> 5;
  const int h = (tid >> 2) & 7;
  const int d4 = tid & 3;
  const unsigned short* vb = (const unsigned short*)value
      + ((size_t)b * 8 + h) * 5376 * 32 + d4 * 8;
  const int cbase = qi * 96 + h * 12;
  char* gb = gbuf + w * 12288;

#pragma unroll
  for (int s0 = 0; s0 < 2; ++s0) {
    const int4 rows = sRow[cbase + s0];
    const int ra[4] = {rows.x, rows.y, rows.z, rows.w};
#pragma unroll
    for (int c = 0; c < 4; ++c)
      gload16((const char*)(vb + (size_t)ra[c] * 32), gb + s0 * 4096 + c * 1024);
  }

  float acc[8] = {};
#pragma unroll
  for (int s = 0; s < 12; ++s) {
    if (s + 2 < 12) {
      const int4 rows = sRow[cbase + s + 2];
      const int ra[4] = {rows.x, rows.y, rows.z, rows.w};
      const int slot = (s + 2) % 3;
#pragma unroll
      for (int c = 0; c < 4; ++c)
        gload16((const char*)(vb + (size_t)ra[c] * 32), gb + slot * 4096 + c * 1024);
    }
    if (s <= 9)       asm volatile("s_waitcnt vmcnt(8)" ::: "memory");
    else if (s == 10) asm volatile("s_waitcnt vmcnt(4)" ::: "memory");
    else              asm volatile("s_waitcnt vmcnt(0)" ::: "memory");
    __builtin_amdgcn_sched_barrier(0);
    const float4 wv = sW[cbase + s];
    const float wa[4] = {wv.x, wv.y, wv.z, wv.w};
    const int slot = s % 3;
#pragma unroll
    for (int c = 0; c < 4; ++c) {
      const uint4 v = *reinterpret_cast<const uint4*>(gb + slot * 4096 + c * 1024 + lane * 16);
      const float wgt = wa[c];
      acc[0] += wgt * bflo(v.x); acc[1] += wgt * bfhi(v.x);
      acc[2] += wgt * bflo(v.y); acc[3] += wgt * bfhi(v.y);
      acc[4] += wgt * bflo(v.z); acc[5] += wgt * bfhi(v.z);
      acc[6] += wgt * bflo(v.w); acc[7] += wgt * bfhi(v.w);
    }
  }

  // ---- fused spatial logits: thread covers dims kq..kq+7 (= h*32+d4*8) ----
  const int kq = (tid & 31) * 8;
  const float* qp = &query[(size_t)(bq0 + qi) * 256 + kq];
  const f32x4 q0 = *reinterpret_cast<const f32x4*>(qp);
  const f32x4 q1 = *reinterpret_cast<const f32x4*>(qp + 4);
  float lg2[20];
#pragma unroll
  for (int c = 0; c < 20; ++c) {
    const f32x4 w0 = *reinterpret_cast<const f32x4*>(&WLt[c * 256 + kq]);
    const f32x4 w1 = *reinterpret_cast<const f32x4*>(&WLt[c * 256 + kq + 4]);
    const f32x4 v0 = *reinterpret_cast<const f32x4*>(&WL2t[c * 256 + kq]);
    const f32x4 v1 = *reinterpret_cast<const f32x4*>(&WL2t[c * 256 + kq + 4]);
    lg2[c] = q0.x * w0.x + q0.y * w0.y + q0.z * w0.z + q0.w * w0.w
           + q1.x * w1.x + q1.y * w1.y + q1.z * w1.z + q1.w * w1.w
           + acc[0] * v0.x + acc[1] * v0.y + acc[2] * v0.z + acc[3] * v0.w
           + acc[4] * v1.x + acc[5] * v1.y + acc[6] * v1.z + acc[7] * v1.w;
  }
#pragma unroll
  for (int c = 0; c < 20; ++c) {
    lg2[c] += __shfl_xor(lg2[c], 1);
    lg2[c] += __shfl_xor(lg2[c], 2);
    lg2[c] += __shfl_xor(lg2[c], 4);
    lg2[c] += __shfl_xor(lg2[c], 8);
    lg2[c] += __shfl_xor(lg2[c], 16);
  }
  if ((tid & 31) == 0) {
    float a[20];
#pragma unroll
    for (int c = 0; c < 20; ++c) a[c] = lg2[c] + cL[c];
#pragma unroll
    for (int hh = 0; hh < 2; ++hh) {
      float mx = -1e30f;
#pragma unroll
      for (int m = 0; m < 10; ++m) mx = fmaxf(mx, a[hh * 10 + m]);
      float s = 0.f;
#pragma unroll
      for (int m = 0; m < 10; ++m) { a[hh * 10 + m] = expf(a[hh * 10 + m] - mx); s += a[hh * 10 + m]; }
      const float inv = 1.f / s;
#pragma unroll
      for (int m = 0; m < 10; ++m) a[hh * 10 + m] *= inv;
    }
#pragma unroll
    for (int m = 0; m < 10; ++m)
      attn_out[(size_t)(bq0 + qi) * 10 + m] = 0.5f * (a[m] + a[10 + m]);
#pragma unroll
    for (int c = 0; c < 20; ++c) ared[qi][c] = a[c];
  }
  __syncthreads();
  if (tid < 20) {
    float s = 0.f;
#pragma unroll
    for (int q2 = 0; q2 < 8; ++q2) s += ared[q2][tid];
    partial[blockIdx.x * 20 + tid] = s;
  }
}

// final2: cls cross-attention + classification head. One block per b.
// partial is now [4096][20], 128 chunks per batch.
__global__ __launch_bounds__(256) void final2_kernel(
    const float* __restrict__ x_cls, const float* __restrict__ Wq_c,
    const float* __restrict__ bq_c, const float* __restrict__ kv_u,
    const float* __restrict__ kv_n, const float* __restrict__ partial,
    const float* __restrict__ kv_s, const float* __restrict__ Wp_c,
    const float* __restrict__ bp_c, const float* __restrict__ Wp_s,
    const float* __restrict__ bp_s, float* __restrict__ out,
    float* __restrict__ attn_u_out, float* __restrict__ attn_n_out)
{
  const int b = blockIdx.x, tid = threadIdx.x;
  __shared__ float ou[256], osb[256], abar[20], xr[256];
  if (tid < 64)
    *reinterpret_cast<float4*>(&xr[tid * 4]) =
        *reinterpret_cast<const float4*>(&x_cls[(size_t)b * 256 + tid * 4]);
  if (tid >= 64 && tid < 84) {
    const int c = tid - 64;
    float s = 0.f;
    for (int ch = 0; ch < 128; ++ch) s += partial[((size_t)b * 128 + ch) * 20 + c];
    abar[c] = s * (1.0f / 1024.0f);
  }
  __syncthreads();
  if (tid < 64) {
    const int lane = tid;
    float4 q4 = *reinterpret_cast<const float4*>(&bq_c[lane * 4]);
    for (int k = 0; k < 256; ++k) {
      const float xk = xr[k];
      const float4 w = *reinterpret_cast<const float4*>(&Wq_c[(size_t)k * 256 + lane * 4]);
      q4.x += xk * w.x; q4.y += xk * w.y; q4.z += xk * w.z; q4.w += xk * w.w;
    }
    const float scale = 0.08838834764831845f;
    float4 osum = {0.f, 0.f, 0.f, 0.f};
    for (int cs = 0; cs < 2; ++cs) {
      const float* kv = cs ? kv_n : kv_u;
      float* aout = cs ? attn_n_out : attn_u_out;
      float attn[10];
      float mx = -1e30f;
#pragma unroll
      for (int m = 0; m < 10; ++m) {
        const float4 k4 = *reinterpret_cast<const float4*>(&kv[m * 512 + lane * 4]);
        float p = q4.x * k4.x + q4.y * k4.y + q4.z * k4.z + q4.w * k4.w;
        p += __shfl_xor(p, 1);  p += __shfl_xor(p, 2);  p += __shfl_xor(p, 4);
        p += __shfl_xor(p, 8);  p += __shfl_xor(p, 16);
        attn[m] = p * scale;
        mx = fmaxf(mx, attn[m]);
      }
      float s = 0.f;
#pragma unroll
      for (int m = 0; m < 10; ++m) { attn[m] = expf(attn[m] - mx); s += attn[m]; }
      const float inv = 1.f / s;
#pragma unroll
      for (int m = 0; m < 10; ++m) {
        attn[m] *= inv;
        const float am = 0.5f * (attn[m] + __shfl_xor(attn[m], 32));
        if (lane == m) aout[b * 10 + m] = am;
        const float4 v4 = *reinterpret_cast<const float4*>(&kv[m * 512 + 256 + lane * 4]);
        osum.x += attn[m] * v4.x; osum.y += attn[m] * v4.y;
        osum.z += attn[m] * v4.z; osum.w += attn[m] * v4.w;
      }
    }
    *reinterpret_cast<float4*>(&ou[lane * 4]) = osum;
  }
  {
    const int h = tid >> 7, d = tid & 127;
    float s = 0.f;
#pragma unroll
    for (int m = 0; m < 10; ++m) s += abar[h * 10 + m] * kv_s[m * 512 + 256 + h * 128 + d];
    osb[tid] = s;
  }
  __syncthreads();
  if (tid < 200) {
    float acc = 2.f * bp_c[tid] + bp_s[tid];
    for (int dd = 0; dd < 256; ++dd)
      acc += ou[dd] * Wp_c[dd * 200 + tid] + osb[dd] * Wp_s[dd * 200 + tid];
    out[b * 200 + tid] = acc;
  }
}

extern "C" void kernel_launch(void* const* d_in, const int* in_sizes, int n_in,
                              void* d_out, int out_size, void* d_ws, size_t ws_size,
                              hipStream_t stream)
{
  const float* query  = (const float*)d_in[0];
  const float* feats  = (const float*)d_in[1];
  const float* x_cls  = (const float*)d_in[2];
  const float* W_off  = (const float*)d_in[3];
  const float* b_off  = (const float*)d_in[4];
  const float* W_attn = (const float*)d_in[5];
  const float* b_attn = (const float*)d_in[6];
  const float* W_val  = (const float*)d_in[7];
  const float* b_val  = (const float*)d_in[8];
  const float* W_out  = (const float*)d_in[9];
  const float* b_out  = (const float*)d_in[10];
  const float* unsup  = (const float*)d_in[11];
  const float* conc   = (const float*)d_in[12];
  const float* spat   = (const float*)d_in[13];
  const float* Wq_c   = (const float*)d_in[14];
  const float* bq_c   = (const float*)d_in[15];
  const float* Wkv_c  = (const float*)d_in[16];
  const float* bkv_c  = (const float*)d_in[17];
  const float* Wp_c   = (const float*)d_in[18];
  const float* bp_c   = (const float*)d_in[19];
  const float* Wq_s   = (const float*)d_in[20];
  const float* bq_s   = (const float*)d_in[21];
  const float* Wkv_s  = (const float*)d_in[22];
  const float* bkv_s  = (const float*)d_in[23];
  const float* Wp_s   = (const float*)d_in[24];
  const float* bp_s   = (const float*)d_in[25];
  float* out = (float*)d_out;

  const int B = 32, LQ = 1024, LIN = 5376;
  const int MQ = B * LQ;    // 32768
  const int MV = B * LIN;   // 172032

  char* p = (char*)d_ws;
  __hip_bfloat16* value = (__hip_bfloat16*)p;   p += (size_t)MV * 256 * 2;   // 88MB (head-major)
  float* offlog   = (float*)p;                  p += (size_t)MQ * 320 * 4;   // 42MB
  char* imgV      = p;                          p += 4 * 32768;
  char* imgQ      = p;                          p += 4 * 40960;
  float* bpack    = (float*)p;                  p += 320 * 4;
  float* kv_u     = (float*)p;                  p += 5120 * 4;
  float* kv_n     = (float*)p;                  p += 5120 * 4;
  float* kv_s     = (float*)p;                  p += 5120 * 4;
  float* WLt      = (float*)p;                  p += 5120 * 4;
  float* WL2t     = (float*)p;                  p += 5120 * 4;
  float* cL       = (float*)p;                  p += 32 * 4;
  float* partial  = (float*)p;                  p += 4096 * 20 * 4;

  dim3 blk(256);
  // merged prep: weight images + kv + spatial fold
  prep_all<<<dim3(600), blk, 0, stream>>>(
      W_val, W_off, b_off, W_attn, b_attn, imgV, imgQ, bpack,
      unsup, conc, spat, Wkv_c, bkv_c, Wkv_s, bkv_s, kv_u, kv_n, kv_s,
      Wq_s, bq_s, W_out, b_out, WLt, WL2t, cL);
  // value = feats @ W_val + b_val  (HEAD-MAJOR output)
  gemm_f32a<__hip_bfloat16, 256, 4, true><<<dim3(MV / 128), dim3(512), 0, stream>>>(
      feats, imgV, b_val, value);
  // offlog = query @ [W_off|W_attn|0] + bpack  (N=320 padded)
  gemm_f32a<float, 320, 2, false><<<dim3(MQ / 128), dim3(512), 0, stream>>>(
      query, imgQ, bpack, offlog);
  // deformable sampling + fused spatial branch (attn_s + abar partials)
  msda_sp<<<dim3(MQ / 8), blk, 0, stream>>>(
      offlog, value, query, WLt, WL2t, cL, out + 7040, partial);
  // cls + final head (fused)
  final2_kernel<<<dim3(B), blk, 0, stream>>>(
      x_cls, Wq_c, bq_c, kv_u, kv_n, partial, kv_s, Wp_c, bp_c, Wp_s, bp_s,
      out, out + 6400, out + 6720);
}

// Round 16
// 289.774 us; speedup vs baseline: 1.1440x; 1.1440x over previous
//
#include <hip/hip_runtime.h>
#include <hip/hip_bf16.h>

// ---------------------------------------------------------------------------
// B=32, LQ=1024, LIN=5376, D=256, NH=8, L=3, P=4, DH=32, NH_CA=2, M=10, NCLS=200
// Outputs (f32): out[6400) | attn_u[320) | attn_n[320) | attn_s[327680)
// Round-14 structure (317us, best) + ONE change: qlog = scale*query@WLt + cL
// folded into the offlog GEMM's previously-zero padded columns 288..307
// (fold blocks write WLt into imgQ col 288+j and cL into bpack[288+j]).
// spatial_kernel v2 reads qlog from offlog; drops query read + WLt staging.
// ---------------------------------------------------------------------------

typedef __attribute__((ext_vector_type(8))) short s16x8;
typedef __attribute__((ext_vector_type(4))) float f32x4;

__device__ __forceinline__ void store_val(float* p, float v) { *p = v; }
__device__ __forceinline__ void store_val(__hip_bfloat16* p, float v) { *p = __float2bfloat16(v); }

__device__ __forceinline__ unsigned short f2bf(float x) {
  unsigned int u = __builtin_bit_cast(unsigned int, x);
  u += 0x7FFFu + ((u >> 16) & 1u);  // RNE
  return (unsigned short)(u >> 16);
}
__device__ __forceinline__ float bf2f(unsigned short u) {
  return __builtin_bit_cast(float, (unsigned int)u << 16);
}
__device__ __forceinline__ float bflo(unsigned int u) {
  return __builtin_bit_cast(float, u << 16);
}
__device__ __forceinline__ float bfhi(unsigned int u) {
  return __builtin_bit_cast(float, u & 0xFFFF0000u);
}

__device__ __forceinline__ void gload16(const char* g, char* l) {
  __builtin_amdgcn_global_load_lds(
      (const __attribute__((address_space(1))) unsigned int*)g,
      (__attribute__((address_space(3))) unsigned int*)l, 16, 0, 0);
}

// ---------------------------------------------------------------------------
// prep_all: weight images (BK=64 layout) + bpack | kv | spatial fold.
// Fold block j also writes imgQ col 288+j = WLt[j] (bf16) and bpack[288+j]=cL.
// ---------------------------------------------------------------------------
__global__ __launch_bounds__(256) void prep_all(
    const float* __restrict__ W_val, const float* __restrict__ W_off,
    const float* __restrict__ b_off, const float* __restrict__ W_attn,
    const float* __restrict__ b_attn, char* __restrict__ imgV,
    char* __restrict__ imgQ, float* __restrict__ bpack,
    const float* __restrict__ unsup, const float* __restrict__ conc,
    const float* __restrict__ spat, const float* __restrict__ Wkv_c,
    const float* __restrict__ bkv_c, const float* __restrict__ Wkv_s,
    const float* __restrict__ bkv_s, float* __restrict__ kv_u,
    float* __restrict__ kv_n, float* __restrict__ kv_s,
    const float* __restrict__ Wq_s, const float* __restrict__ bq_s,
    const float* __restrict__ W_out, const float* __restrict__ b_out,
    float* __restrict__ WL2t)
{
  const int bi = blockIdx.x;
  const int tid = threadIdx.x;
  if (bi <= 576) {
    const int n = bi, k = tid;
    if (n == 576) {
      bpack[k] = (k < 192) ? b_off[k] : ((k < 288) ? b_attn[k - 192] : 0.f);
      if (k < 32) bpack[256 + k] = b_attn[64 + k];          // cols 256..287
      else if (k >= 52 && k < 64) bpack[256 + k] = 0.f;     // cols 308..319
      // cols 288..307 (qlog bias = cL) written by fold blocks
      return;
    }
    const int ks = k >> 6;
    const int kb = (k & 63) * 2;
    if (n < 256) {
      const unsigned short v = f2bf(W_val[(size_t)k * 256 + n]);
      *(unsigned short*)(imgV + ks * 32768 + n * 128 + (kb ^ ((n & 7) << 4))) = v;
    } else {
      const int c = n - 256;
      if (c >= 288 && c < 308) return;    // qlog cols owned by fold blocks
      float v = 0.f;
      if (c < 192) v = W_off[(size_t)k * 192 + c];
      else if (c < 288) v = W_attn[(size_t)k * 96 + (c - 192)];
      *(unsigned short*)(imgQ + ks * 40960 + c * 128 + (kb ^ ((c & 7) << 4))) = f2bf(v);
    }
    return;
  }
  if (bi <= 579) {     // kv projections
    const int j = bi - 577;
    const float* src = (j == 0) ? unsup : ((j == 1) ? conc : spat);
    const float* W   = (j < 2) ? Wkv_c : Wkv_s;
    const float* bb  = (j < 2) ? bkv_c : bkv_s;
    float* dst       = (j == 0) ? kv_u : ((j == 1) ? kv_n : kv_s);
    __shared__ float s[2560];
    for (int i = tid; i < 2560; i += 256) s[i] = src[i];
    __syncthreads();
    for (int o = tid; o < 5120; o += 256) {
      const int m = o >> 9, n = o & 511;
      float acc = bb[n];
      for (int k = 0; k < 256; ++k) acc += s[m * 256 + k] * W[(size_t)k * 512 + n];
      dst[o] = acc;
    }
    return;
  }
  {                    // spatial fold
    const int j = bi - 580;
    const int h = j / 10, m = j % 10;
    __shared__ float kk[128], wl[256], bred[256];
    if (tid < 128) {
      const int n = h * 128 + tid;
      float acc = bkv_s[n];
      for (int k = 0; k < 256; ++k) acc += spat[m * 256 + k] * Wkv_s[(size_t)k * 512 + n];
      kk[tid] = acc;
    }
    __syncthreads();
    float acc = 0.f;
    for (int e = 0; e < 128; ++e) acc += Wq_s[(size_t)tid * 256 + h * 128 + e] * kk[e];
    wl[tid] = acc;
    __syncthreads();
    float acc2 = 0.f;
    for (int t = 0; t < 256; ++t) acc2 += W_out[(size_t)tid * 256 + t] * wl[t];
    const float scale = 0.08838834764831845f;
    // qlog weight column into imgQ (col 288+j), bf16 swizzled
    {
      const int col = 288 + j;
      const int ks2 = tid >> 6, kb2 = (tid & 63) * 2;
      *(unsigned short*)(imgQ + ks2 * 40960 + col * 128 + (kb2 ^ ((col & 7) << 4))) =
          f2bf(scale * acc);
    }
    WL2t[j * 256 + tid] = scale * acc2;
    bred[tid] = b_out[tid] * wl[tid] + ((tid < 128) ? bq_s[h * 128 + tid] * kk[tid] : 0.f);
    __syncthreads();
    for (int s = 128; s > 0; s >>= 1) {
      if (tid < s) bred[tid] += bred[tid + s];
      __syncthreads();
    }
    if (tid == 0) bpack[288 + j] = scale * bred[0];   // cL -> qlog bias
  }
}

// ---------------------------------------------------------------------------
// GEMM (round-10/11 proven): C = A[M,256](f32) @ Bimg + bias.
// HM: head-major C layout [b*8+h][5376][32] (value GEMM only).
// ---------------------------------------------------------------------------
template <typename OT, int NCOLS, int MINW, bool HM>
__global__ __launch_bounds__(512, MINW) void gemm_f32a(
    const float* __restrict__ A, const char* __restrict__ Bimg,
    const float* __restrict__ bias, OT* __restrict__ C)
{
  constexpr int NFR = NCOLS / 64;
  __shared__ char sAf[32768];
  __shared__ char sBb[NCOLS * 128];

  const int tid = threadIdx.x;
  const int lane = tid & 63;
  const int w = tid >> 6;
  const int wr = (w >> 2) * 64;
  const int wc = (w & 3) * (NCOLS / 4);
  const int l15 = lane & 15;
  const int lg = lane >> 4;
  const int m0 = blockIdx.x * 128;

  int asrc[4];
#pragma unroll
  for (int i = 0; i < 4; ++i) {
    const int slot = w * 256 + i * 64 + lane;
    const int row = slot >> 4;
    const int c = (slot & 15) ^ (row & 7);
    asrc[i] = row * 256 + c * 4;
  }
  const float* Abase = A + (size_t)m0 * 256;

  f32x4 acc[4][NFR] = {};

#pragma unroll
  for (int ks = 0; ks < 4; ++ks) {
    if (ks) __syncthreads();
    {
      char* la = sAf + w * 4096;
#pragma unroll
      for (int i = 0; i < 4; ++i)
        gload16((const char*)(Abase + ks * 64 + asrc[i]), la + i * 1024);
      const char* gb = Bimg + ks * (NCOLS * 128) + w * (NCOLS * 16) + lane * 16;
      char* lb = sBb + w * (NCOLS * 16);
#pragma unroll
      for (int i = 0; i < NFR; ++i)
        gload16(gb + i * 1024, lb + i * 1024);
    }
    __syncthreads();
#pragma unroll
    for (int kk = 0; kk < 2; ++kk) {
      const int c0 = kk * 8 + lg * 2;
      s16x8 af[4];
#pragma unroll
      for (int mf = 0; mf < 4; ++mf) {
        const int row = wr + mf * 16 + l15;
        const int sw = row & 7;
        const f32x4 lo = *reinterpret_cast<const f32x4*>(
            sAf + row * 256 + ((c0 ^ sw) * 16));
        const f32x4 hi = *reinterpret_cast<const f32x4*>(
            sAf + row * 256 + (((c0 + 1) ^ sw) * 16));
        uint4 u;
        u.x = (unsigned)f2bf(lo[0]) | ((unsigned)f2bf(lo[1]) << 16);
        u.y = (unsigned)f2bf(lo[2]) | ((unsigned)f2bf(lo[3]) << 16);
        u.z = (unsigned)f2bf(hi[0]) | ((unsigned)f2bf(hi[1]) << 16);
        u.w = (unsigned)f2bf(hi[2]) | ((unsigned)f2bf(hi[3]) << 16);
        af[mf] = __builtin_bit_cast(s16x8, u);
      }
      const int kb = kk * 64 + lg * 16;
      s16x8 bf[NFR];
#pragma unroll
      for (int nf = 0; nf < NFR; ++nf) {
        const int col = wc + nf * 16 + l15;
        bf[nf] = *reinterpret_cast<const s16x8*>(sBb + col * 128 + (kb ^ ((col & 7) << 4)));
      }
#pragma unroll
      for (int mf = 0; mf < 4; ++mf)
#pragma unroll
        for (int nf = 0; nf < NFR; ++nf)
          acc[mf][nf] = __builtin_amdgcn_mfma_f32_16x16x32_bf16(af[mf], bf[nf], acc[mf][nf], 0, 0, 0);
    }
  }

#pragma unroll
  for (int nf = 0; nf < NFR; ++nf) {
    const int col = wc + nf * 16 + l15;
    const float bb = bias[col];
#pragma unroll
    for (int mf = 0; mf < 4; ++mf) {
#pragma unroll
      for (int j = 0; j < 4; ++j) {
        const int row = m0 + wr + mf * 16 + lg * 4 + j;
        const float v = acc[mf][nf][j] + bb;
        if constexpr (HM) {
          const unsigned rb = (unsigned)row / 5376u;
          const unsigned rr = (unsigned)row - rb * 5376u;
          store_val(&C[(((size_t)rb * 8 + (col >> 5)) * 5376 + rr) * 32 + (col & 31)], v);
        } else {
          store_val(&C[(size_t)row * NCOLS + col], v);
        }
      }
    }
  }
}

// ---------------------------------------------------------------------------
// MSDA v4 (round-14 proven): 8 queries/block, head-major value, depth-3
// gload_lds gather pipeline, counted vmcnt(8). offlog row stride = 320.
// ---------------------------------------------------------------------------
__global__ __launch_bounds__(256) void msda_v4(
    const float* __restrict__ offlog, const __hip_bfloat16* __restrict__ value,
    __hip_bfloat16* __restrict__ msda_out)
{
  const int bq0 = blockIdx.x * 8;
  const int b = bq0 >> 10;
  const int tid = threadIdx.x;
  __shared__ float aw[768];
  __shared__ int4 sRow[768];
  __shared__ float4 sW[768];
  __shared__ __align__(16) char gbuf[4 * 3 * 4096];

  if (tid < 64) {
    const int qi = tid >> 3, h = tid & 7;
    const float* lp = &offlog[(size_t)(bq0 + qi) * 320 + 192 + h * 12];
    float e[12];
    float mx = -1e30f;
#pragma unroll
    for (int i = 0; i < 12; ++i) { e[i] = lp[i]; mx = fmaxf(mx, e[i]); }
    float s = 0.f;
#pragma unroll
    for (int i = 0; i < 12; ++i) { e[i] = expf(e[i] - mx); s += e[i]; }
    const float inv = 1.f / s;
#pragma unroll
    for (int i = 0; i < 12; ++i) aw[qi * 96 + h * 12 + i] = e[i] * inv;
  }
  __syncthreads();

#pragma unroll
  for (int k = 0; k < 3; ++k) {
    const int j = k * 256 + tid;
    const int qi = j / 96, cc = j - qi * 96;
    const int q = (bq0 + qi) & 1023;
    const int h = cc / 12, r = cc - h * 12, l = r >> 2, p_ = r & 3;
    const int WHl[3] = {64, 32, 16};
    const int St[3] = {0, 4096, 5120};
    const float2 o2 = *reinterpret_cast<const float2*>(
        &offlog[(size_t)(bq0 + qi) * 320 + h * 24 + l * 8 + p_ * 2]);
    const float refx = ((q & 31) + 0.5f) * (1.0f / 32.0f);
    const float refy = ((q >> 5) + 0.5f) * (1.0f / 32.0f);
    const int WH = WHl[l];
    const float fw = (float)WH;
    const float lx = (refx + o2.x / fw) * fw - 0.5f;
    const float ly = (refy + o2.y / fw) * fw - 0.5f;
    const float fx = floorf(lx), fy = floorf(ly);
    const int x0 = (int)fx, y0 = (int)fy;
    const float dx = lx - fx, dy = ly - fy;
    const float a = aw[j];
    int rows[4];
    float ws[4];
#pragma unroll
    for (int c = 0; c < 4; ++c) {
      const int ix = x0 + (c & 1), iy = y0 + (c >> 1);
      const float wb = ((c & 1) ? dx : 1.f - dx) * ((c >> 1) ? dy : 1.f - dy);
      const bool valid = (ix >= 0) && (ix < WH) && (iy >= 0) && (iy < WH);
      const int cx = min(max(ix, 0), WH - 1);
      const int cy = min(max(iy, 0), WH - 1);
      rows[c] = St[l] + cy * WH + cx;
      ws[c] = valid ? wb * a : 0.f;
    }
    sRow[j] = int4{rows[0], rows[1], rows[2], rows[3]};
    sW[j] = float4{ws[0], ws[1], ws[2], ws[3]};
  }
  __syncthreads();

  const int w = tid >> 6;
  const int lane = tid & 63;
  const int qi = tid >> 5;
  const int h = (tid >> 2) & 7;
  const int d4 = tid & 3;
  const unsigned short* vb = (const unsigned short*)value
      + ((size_t)b * 8 + h) * 5376 * 32 + d4 * 8;
  const int cbase = qi * 96 + h * 12;
  char* gb = gbuf + w * 12288;

#pragma unroll
  for (int s0 = 0; s0 < 2; ++s0) {
    const int4 rows = sRow[cbase + s0];
    const int ra[4] = {rows.x, rows.y, rows.z, rows.w};
#pragma unroll
    for (int c = 0; c < 4; ++c)
      gload16((const char*)(vb + (size_t)ra[c] * 32), gb + s0 * 4096 + c * 1024);
  }

  float acc[8] = {};
#pragma unroll
  for (int s = 0; s < 12; ++s) {
    if (s + 2 < 12) {
      const int4 rows = sRow[cbase + s + 2];
      const int ra[4] = {rows.x, rows.y, rows.z, rows.w};
      const int slot = (s + 2) % 3;
#pragma unroll
      for (int c = 0; c < 4; ++c)
        gload16((const char*)(vb + (size_t)ra[c] * 32), gb + slot * 4096 + c * 1024);
    }
    if (s <= 9)       asm volatile("s_waitcnt vmcnt(8)" ::: "memory");
    else if (s == 10) asm volatile("s_waitcnt vmcnt(4)" ::: "memory");
    else              asm volatile("s_waitcnt vmcnt(0)" ::: "memory");
    __builtin_amdgcn_sched_barrier(0);
    const float4 wv = sW[cbase + s];
    const float wa[4] = {wv.x, wv.y, wv.z, wv.w};
    const int slot = s % 3;
#pragma unroll
    for (int c = 0; c < 4; ++c) {
      const uint4 v = *reinterpret_cast<const uint4*>(gb + slot * 4096 + c * 1024 + lane * 16);
      const float wgt = wa[c];
      acc[0] += wgt * bflo(v.x); acc[1] += wgt * bfhi(v.x);
      acc[2] += wgt * bflo(v.y); acc[3] += wgt * bfhi(v.y);
      acc[4] += wgt * bflo(v.z); acc[5] += wgt * bfhi(v.z);
      acc[6] += wgt * bflo(v.w); acc[7] += wgt * bfhi(v.w);
    }
  }
  uint4 o;
  o.x = (unsigned)f2bf(acc[0]) | ((unsigned)f2bf(acc[1]) << 16);
  o.y = (unsigned)f2bf(acc[2]) | ((unsigned)f2bf(acc[3]) << 16);
  o.z = (unsigned)f2bf(acc[4]) | ((unsigned)f2bf(acc[5]) << 16);
  o.w = (unsigned)f2bf(acc[6]) | ((unsigned)f2bf(acc[7]) << 16);
  *reinterpret_cast<uint4*>(
      (unsigned short*)msda_out + (size_t)(bq0 + qi) * 256 + h * 32 + d4 * 8) = o;
}

// ---------------------------------------------------------------------------
// spatial v2: logits = qlog (offlog cols 288..307) + msda@WL2t -> softmax ->
// attn_s + per-block abar partial. 128 rows/block, 2 threads/row.
// ---------------------------------------------------------------------------
__global__ __launch_bounds__(256) void spatial_kernel(
    const float* __restrict__ offlog, const __hip_bfloat16* __restrict__ msda,
    const float* __restrict__ WL2t, float* __restrict__ attn_out,
    float* __restrict__ partial)
{
  __shared__ float wl2s[20][256];
  __shared__ float red[128][20];
  const int tid = threadIdx.x;
  for (int i = tid; i < 5120; i += 256) wl2s[i >> 8][i & 255] = WL2t[i];
  const int row_local = tid >> 1;
  const int half = tid & 1;
  const int row = blockIdx.x * 128 + row_local;
  float acc[20];
  if (half == 0) {
#pragma unroll
    for (int c = 0; c < 20; ++c) acc[c] = offlog[(size_t)row * 320 + 288 + c];
  } else {
#pragma unroll
    for (int c = 0; c < 20; ++c) acc[c] = 0.f;
  }
  __syncthreads();

  const unsigned short* mp = (const unsigned short*)msda + (size_t)row * 256 + half * 128;
  const int kbase = half * 128;
  for (int k = 0; k < 128; k += 8) {
    const uint4 mm = *reinterpret_cast<const uint4*>(mp + k);
    const float m0 = bflo(mm.x), m1 = bfhi(mm.x), m2 = bflo(mm.y), m3 = bfhi(mm.y);
    const float m4 = bflo(mm.z), m5 = bfhi(mm.z), m6 = bflo(mm.w), m7 = bfhi(mm.w);
#pragma unroll
    for (int c = 0; c < 20; ++c) {
      const f32x4 v0 = *reinterpret_cast<const f32x4*>(&wl2s[c][kbase + k]);
      const f32x4 v1 = *reinterpret_cast<const f32x4*>(&wl2s[c][kbase + k + 4]);
      acc[c] += m0 * v0.x + m1 * v0.y + m2 * v0.z + m3 * v0.w
              + m4 * v1.x + m5 * v1.y + m6 * v1.z + m7 * v1.w;
    }
  }
  if (half == 1) {
#pragma unroll
    for (int c = 0; c < 20; ++c) red[row_local][c] = acc[c];
  }
  __syncthreads();
  if (half == 0) {
    float a[20];
#pragma unroll
    for (int c = 0; c < 20; ++c) a[c] = acc[c] + red[row_local][c];
#pragma unroll
    for (int h = 0; h < 2; ++h) {
      float mx = -1e30f;
#pragma unroll
      for (int m = 0; m < 10; ++m) mx = fmaxf(mx, a[h * 10 + m]);
      float s = 0.f;
#pragma unroll
      for (int m = 0; m < 10; ++m) { a[h * 10 + m] = expf(a[h * 10 + m] - mx); s += a[h * 10 + m]; }
      const float inv = 1.f / s;
#pragma unroll
      for (int m = 0; m < 10; ++m) a[h * 10 + m] *= inv;
    }
#pragma unroll
    for (int m = 0; m < 10; ++m)
      attn_out[(size_t)row * 10 + m] = 0.5f * (a[m] + a[10 + m]);
#pragma unroll
    for (int c = 0; c < 20; ++c) red[row_local][c] = a[c];
  }
  __syncthreads();
  if (tid < 20) {
    float s = 0.f;
    for (int r = 0; r < 128; ++r) s += red[r][tid];
    partial[blockIdx.x * 20 + tid] = s;
  }
}

// final2: cls cross-attention + classification head. One block per b.
__global__ __launch_bounds__(256) void final2_kernel(
    const float* __restrict__ x_cls, const float* __restrict__ Wq_c,
    const float* __restrict__ bq_c, const float* __restrict__ kv_u,
    const float* __restrict__ kv_n, const float* __restrict__ partial,
    const float* __restrict__ kv_s, const float* __restrict__ Wp_c,
    const float* __restrict__ bp_c, const float* __restrict__ Wp_s,
    const float* __restrict__ bp_s, float* __restrict__ out,
    float* __restrict__ attn_u_out, float* __restrict__ attn_n_out)
{
  const int b = blockIdx.x, tid = threadIdx.x;
  __shared__ float ou[256], osb[256], abar[20], xr[256];
  if (tid < 64)
    *reinterpret_cast<float4*>(&xr[tid * 4]) =
        *reinterpret_cast<const float4*>(&x_cls[(size_t)b * 256 + tid * 4]);
  if (tid >= 64 && tid < 84) {
    const int c = tid - 64;
    float s = 0.f;
    for (int ch = 0; ch < 8; ++ch) s += partial[(b * 8 + ch) * 20 + c];
    abar[c] = s * (1.0f / 1024.0f);
  }
  __syncthreads();
  if (tid < 64) {
    const int lane = tid;
    float4 q4 = *reinterpret_cast<const float4*>(&bq_c[lane * 4]);
    for (int k = 0; k < 256; ++k) {
      const float xk = xr[k];
      const float4 w = *reinterpret_cast<const float4*>(&Wq_c[(size_t)k * 256 + lane * 4]);
      q4.x += xk * w.x; q4.y += xk * w.y; q4.z += xk * w.z; q4.w += xk * w.w;
    }
    const float scale = 0.08838834764831845f;
    float4 osum = {0.f, 0.f, 0.f, 0.f};
    for (int cs = 0; cs < 2; ++cs) {
      const float* kv = cs ? kv_n : kv_u;
      float* aout = cs ? attn_n_out : attn_u_out;
      float attn[10];
      float mx = -1e30f;
#pragma unroll
      for (int m = 0; m < 10; ++m) {
        const float4 k4 = *reinterpret_cast<const float4*>(&kv[m * 512 + lane * 4]);
        float p = q4.x * k4.x + q4.y * k4.y + q4.z * k4.z + q4.w * k4.w;
        p += __shfl_xor(p, 1);  p += __shfl_xor(p, 2);  p += __shfl_xor(p, 4);
        p += __shfl_xor(p, 8);  p += __shfl_xor(p, 16);
        attn[m] = p * scale;
        mx = fmaxf(mx, attn[m]);
      }
      float s = 0.f;
#pragma unroll
      for (int m = 0; m < 10; ++m) { attn[m] = expf(attn[m] - mx); s += attn[m]; }
      const float inv = 1.f / s;
#pragma unroll
      for (int m = 0; m < 10; ++m) {
        attn[m] *= inv;
        const float am = 0.5f * (attn[m] + __shfl_xor(attn[m], 32));
        if (lane == m) aout[b * 10 + m] = am;
        const float4 v4 = *reinterpret_cast<const float4*>(&kv[m * 512 + 256 + lane * 4]);
        osum.x += attn[m] * v4.x; osum.y += attn[m] * v4.y;
        osum.z += attn[m] * v4.z; osum.w += attn[m] * v4.w;
      }
    }
    *reinterpret_cast<float4*>(&ou[lane * 4]) = osum;
  }
  {
    const int h = tid >> 7, d = tid & 127;
    float s = 0.f;
#pragma unroll
    for (int m = 0; m < 10; ++m) s += abar[h * 10 + m] * kv_s[m * 512 + 256 + h * 128 + d];
    osb[tid] = s;
  }
  __syncthreads();
  if (tid < 200) {
    float acc = 2.f * bp_c[tid] + bp_s[tid];
    for (int dd = 0; dd < 256; ++dd)
      acc += ou[dd] * Wp_c[dd * 200 + tid] + osb[dd] * Wp_s[dd * 200 + tid];
    out[b * 200 + tid] = acc;
  }
}

extern "C" void kernel_launch(void* const* d_in, const int* in_sizes, int n_in,
                              void* d_out, int out_size, void* d_ws, size_t ws_size,
                              hipStream_t stream)
{
  const float* query  = (const float*)d_in[0];
  const float* feats  = (const float*)d_in[1];
  const float* x_cls  = (const float*)d_in[2];
  const float* W_off  = (const float*)d_in[3];
  const float* b_off  = (const float*)d_in[4];
  const float* W_attn = (const float*)d_in[5];
  const float* b_attn = (const float*)d_in[6];
  const float* W_val  = (const float*)d_in[7];
  const float* b_val  = (const float*)d_in[8];
  const float* W_out  = (const float*)d_in[9];
  const float* b_out  = (const float*)d_in[10];
  const float* unsup  = (const float*)d_in[11];
  const float* conc   = (const float*)d_in[12];
  const float* spat   = (const float*)d_in[13];
  const float* Wq_c   = (const float*)d_in[14];
  const float* bq_c   = (const float*)d_in[15];
  const float* Wkv_c  = (const float*)d_in[16];
  const float* bkv_c  = (const float*)d_in[17];
  const float* Wp_c   = (const float*)d_in[18];
  const float* bp_c   = (const float*)d_in[19];
  const float* Wq_s   = (const float*)d_in[20];
  const float* bq_s   = (const float*)d_in[21];
  const float* Wkv_s  = (const float*)d_in[22];
  const float* bkv_s  = (const float*)d_in[23];
  const float* Wp_s   = (const float*)d_in[24];
  const float* bp_s   = (const float*)d_in[25];
  float* out = (float*)d_out;

  const int B = 32, LQ = 1024, LIN = 5376;
  const int MQ = B * LQ;    // 32768
  const int MV = B * LIN;   // 172032

  char* p = (char*)d_ws;
  __hip_bfloat16* value = (__hip_bfloat16*)p;   p += (size_t)MV * 256 * 2;   // 88MB (head-major)
  float* offlog   = (float*)p;                  p += (size_t)MQ * 320 * 4;   // 42MB
  __hip_bfloat16* msda = (__hip_bfloat16*)p;    p += (size_t)MQ * 256 * 2;   // 17MB
  char* imgV      = p;                          p += 4 * 32768;
  char* imgQ      = p;                          p += 4 * 40960;
  float* bpack    = (float*)p;                  p += 320 * 4;
  float* kv_u     = (float*)p;                  p += 5120 * 4;
  float* kv_n     = (float*)p;                  p += 5120 * 4;
  float* kv_s     = (float*)p;                  p += 5120 * 4;
  float* WL2t     = (float*)p;                  p += 5120 * 4;
  float* partial  = (float*)p;                  p += 256 * 20 * 4;

  dim3 blk(256);
  // merged prep: weight images (incl. qlog cols) + kv + spatial fold
  prep_all<<<dim3(600), blk, 0, stream>>>(
      W_val, W_off, b_off, W_attn, b_attn, imgV, imgQ, bpack,
      unsup, conc, spat, Wkv_c, bkv_c, Wkv_s, bkv_s, kv_u, kv_n, kv_s,
      Wq_s, bq_s, W_out, b_out, WL2t);
  // value = feats @ W_val + b_val  (HEAD-MAJOR output)
  gemm_f32a<__hip_bfloat16, 256, 4, true><<<dim3(MV / 128), dim3(512), 0, stream>>>(
      feats, imgV, b_val, value);
  // offlog = query @ [W_off|W_attn|WLt|0] + bpack  (cols 288..307 = qlog)
  gemm_f32a<float, 320, 2, false><<<dim3(MQ / 128), dim3(512), 0, stream>>>(
      query, imgQ, bpack, offlog);
  // deformable sampling (head-major gather; depth-3 gload_lds pipeline)
  msda_v4<<<dim3(MQ / 8), blk, 0, stream>>>(offlog, value, msda);
  // spatial v2: qlog + msda@WL2t
  spatial_kernel<<<dim3(MQ / 128), blk, 0, stream>>>(
      offlog, msda, WL2t, out + 7040, partial);
  // cls + final head (fused)
  final2_kernel<<<dim3(B), blk, 0, stream>>>(
      x_cls, Wq_c, bq_c, kv_u, kv_n, partial, kv_s, Wp_c, bp_c, Wp_s, bp_s,
      out, out + 6400, out + 6720);
}